// Round 9
// baseline (475.708 us; speedup 1.0000x reference)
//
#include <hip/hip_runtime.h>
#include <stdint.h>

#define N_ROWS 12288
#define GSZ (128 * 12288)  // elements per gt matrix (bf16)
#define NPART_OFF (9437184 / 4)          // float offset of node partials in ws
#define EPART_OFF ((9437184 + 6291456) / 4)

typedef __attribute__((ext_vector_type(8))) short bf16x8;
typedef __attribute__((ext_vector_type(4))) float f32x4;

union frag_u { bf16x8 v; uint32_t u[4]; };

__device__ __forceinline__ uint32_t f2bf(float x) {
  union { float f; uint32_t u; } c; c.f = x;
  return (c.u + 0x7FFFu + ((c.u >> 16) & 1u)) >> 16;
}
__device__ __forceinline__ uint32_t pk_bf(float a, float b) {
  return f2bf(a) | (f2bf(b) << 16);
}
__device__ __forceinline__ uint32_t sgn_h(float a) {
  return a > 0.f ? 0x3F80u : (a < 0.f ? 0xBF80u : 0u);
}
__device__ __forceinline__ uint32_t pk_sgn(float a, float b) {
  return sgn_h(a) | (sgn_h(b) << 16);
}

#define MFMA __builtin_amdgcn_mfma_f32_16x16x32_bf16

// ---------------------------------------------------------------------------
// Kernel 1: from W build three bf16 TRANSPOSED matrices in gt:
//   mat0 = Gm = (feats@Wtop - feats@Wbot)/2   (for S = sgn(node_adj))
//   mat1 = Gp = (feats@Wtop + feats@Wbot)/2   (for A = |S|)
//   mat2 = Ge = feats@edge_w
// gt[m][n][k] = G[k][n];  pos@G1+neg@G2 == S@Gm + A@Gp.
// ---------------------------------------------------------------------------
__global__ __launch_bounds__(256) void gw_kernel(
    const float* __restrict__ feats, const float* __restrict__ node_w,
    const float* __restrict__ edge_w, uint16_t* __restrict__ gt) {
  __shared__ float lf[16 * 128];
  const int t = threadIdx.x;
  const int kb = blockIdx.x * 16;
  {
    const float4* src = (const float4*)(feats + (size_t)kb * 128);
    float4* dst = (float4*)lf;
    dst[t] = src[t];
    dst[t + 256] = src[t + 256];
  }
  __syncthreads();
  const int n = t & 127;
  const int rh = t >> 7;

  float accT[8], accB[8];
#pragma unroll
  for (int q = 0; q < 8; ++q) { accT[q] = 0.f; accB[q] = 0.f; }
  {
    const float* WT = node_w + n;
    const float* WB = node_w + 128 * 128 + n;
    for (int i = 0; i < 128; i += 2) {
      const float t0 = WT[(i + 0) * 128], t1 = WT[(i + 1) * 128];
      const float b0 = WB[(i + 0) * 128], b1 = WB[(i + 1) * 128];
#pragma unroll
      for (int q = 0; q < 8; ++q) {
        const float f0 = lf[(rh * 8 + q) * 128 + i];
        const float f1 = lf[(rh * 8 + q) * 128 + i + 1];
        accT[q] = fmaf(f1, t1, fmaf(f0, t0, accT[q]));
        accB[q] = fmaf(f1, b1, fmaf(f0, b0, accB[q]));
      }
    }
  }
  {
    uint4 o;  // Gm
    o.x = pk_bf((accT[0] - accB[0]) * 0.5f, (accT[1] - accB[1]) * 0.5f);
    o.y = pk_bf((accT[2] - accB[2]) * 0.5f, (accT[3] - accB[3]) * 0.5f);
    o.z = pk_bf((accT[4] - accB[4]) * 0.5f, (accT[5] - accB[5]) * 0.5f);
    o.w = pk_bf((accT[6] - accB[6]) * 0.5f, (accT[7] - accB[7]) * 0.5f);
    *(uint4*)(gt + (size_t)n * N_ROWS + kb + rh * 8) = o;
    uint4 p;  // Gp
    p.x = pk_bf((accT[0] + accB[0]) * 0.5f, (accT[1] + accB[1]) * 0.5f);
    p.y = pk_bf((accT[2] + accB[2]) * 0.5f, (accT[3] + accB[3]) * 0.5f);
    p.z = pk_bf((accT[4] + accB[4]) * 0.5f, (accT[5] + accB[5]) * 0.5f);
    p.w = pk_bf((accT[6] + accB[6]) * 0.5f, (accT[7] + accB[7]) * 0.5f);
    *(uint4*)(gt + GSZ + (size_t)n * N_ROWS + kb + rh * 8) = p;
  }
  {
    float accE[8];
#pragma unroll
    for (int q = 0; q < 8; ++q) accE[q] = 0.f;
    const float* WE = edge_w + n;
    for (int i = 0; i < 128; i += 2) {
      const float e0 = WE[(i + 0) * 128], e1 = WE[(i + 1) * 128];
#pragma unroll
      for (int q = 0; q < 8; ++q) {
        const float f0 = lf[(rh * 8 + q) * 128 + i];
        const float f1 = lf[(rh * 8 + q) * 128 + i + 1];
        accE[q] = fmaf(f1, e1, fmaf(f0, e0, accE[q]));
      }
    }
    uint4 o;
    o.x = pk_bf(accE[0], accE[1]);
    o.y = pk_bf(accE[2], accE[3]);
    o.z = pk_bf(accE[4], accE[5]);
    o.w = pk_bf(accE[6], accE[7]);
    *(uint4*)(gt + 2 * (size_t)GSZ + (size_t)n * N_ROWS + kb + rh * 8) = o;
  }
}

// ---------------------------------------------------------------------------
// Kernel 2: K-sliced partials with FAT DRAM BURSTS. 1536 blocks x 512 thr
// (8 waves), 2 blocks/CU (LDS 64KB, VGPR<=128). BM=64, BK=128 -> each
// adjacency row is fetched in a 512B contiguous burst per iteration
// (12 iters per 1536-wide K-slice). slice = bid&7 = XCD (gt slice in L2).
// LDS: 2 bufs x [S(64x128) | E(64x128)] bf16; granule swizzle g^(row&7)
// (conflict-free b128, G4). Node needs ONE staged matrix: S=sgn(adj);
// A=|S| derived by AND in-register. accn += S@Gm + A@Gp; acce += E@Ge.
// Per iter: compute(i) -> pack(i+1) -> issue adj(i+2) -> lgkm+raw barrier
// (no vmcnt drain; adjacency always issued one full iter before its wait).
// ---------------------------------------------------------------------------
__global__ __launch_bounds__(512, 4) void fgc_main(
    const float* __restrict__ node_adj, const float* __restrict__ edge_adj,
    const uint16_t* __restrict__ gt, float* __restrict__ node_part,
    float* __restrict__ edge_part) {
  __shared__ __align__(128) char smem[65536];
  const int t = threadIdx.x;
  const int l = t & 63;
  const int w = t >> 6;
  const int bid = blockIdx.x;
  const int slice = bid & 7;
  const int row0 = (bid >> 3) * 64;
  const int k0 = slice * 1536;

  // staging: threads 0-255 stage node (S), 256-511 stage edge (E).
  // thread -> (row sr, 128B chunk so): loads 32 consecutive f32.
  const int ts = t & 255;
  const int sr = ts >> 2, so = ts & 3;
  const bool isNode = (t < 256);
  const float* src = (isNode ? node_adj : edge_adj) +
                     (size_t)(row0 + sr) * N_ROWS + k0 + so * 32;
  const int matOff = isNode ? 0 : 16384;
  int wOffs[4];
#pragma unroll
  for (int j = 0; j < 4; ++j)
    wOffs[j] = matOff + sr * 256 + (((so * 4 + j) ^ (sr & 7)) * 16);

  // consumer fragment addressing: row = mf*16 + r15, granule (ks*4+gq)^rx
  const int r15 = l & 15;
  const int gq = l >> 4;
  const int rx = r15 & 7;

  // B lane base: n = w*16 + r15, k = k0 + i*128 + ks*32 + gq*8
  const uint16_t* gB = gt + (size_t)(w * 16 + r15) * N_ROWS + k0 + gq * 8;

  f32x4 accn[4], acce[4];
#pragma unroll
  for (int a = 0; a < 4; ++a) {
    accn[a] = {0.f, 0.f, 0.f, 0.f};
    acce[a] = {0.f, 0.f, 0.f, 0.f};
  }

  float4 rr[8];  // raw f32 adjacency for the NEXT iter (32 floats)

  // ---- prologue: pack(0) -> buf0, issue adj(1), barrier ----
#pragma unroll
  for (int m = 0; m < 8; ++m) rr[m] = *(const float4*)(src + m * 4);
  {
    char* wbuf = smem;
#pragma unroll
    for (int j = 0; j < 4; ++j) {
      const float4 u = rr[2 * j], v = rr[2 * j + 1];
      uint4 P;
      if (isNode) {
        P.x = pk_sgn(u.x, u.y); P.y = pk_sgn(u.z, u.w);
        P.z = pk_sgn(v.x, v.y); P.w = pk_sgn(v.z, v.w);
      } else {
        P.x = pk_bf(u.x, u.y);  P.y = pk_bf(u.z, u.w);
        P.z = pk_bf(v.x, v.y);  P.w = pk_bf(v.z, v.w);
      }
      *(uint4*)(wbuf + wOffs[j]) = P;
    }
  }
#pragma unroll
  for (int m = 0; m < 8; ++m) rr[m] = *(const float4*)(src + 128 + m * 4);
  asm volatile("s_waitcnt lgkmcnt(0)" ::: "memory");
  __builtin_amdgcn_s_barrier();

#pragma unroll 1
  for (int i = 0; i < 12; ++i) {
    // ---- compute iter i from buf[i&1] ----
    const char* rb = smem + (i & 1) * 32768;
#pragma unroll
    for (int ks = 0; ks < 4; ++ks) {
      const uint16_t* gk = gB + i * 128 + ks * 32;
      const bf16x8 bm = *(const bf16x8*)(gk);
      const bf16x8 bp = *(const bf16x8*)(gk + GSZ);
      const bf16x8 be = *(const bf16x8*)(gk + 2 * GSZ);
#pragma unroll
      for (int mf = 0; mf < 4; ++mf) {
        const int aoff = (mf * 16 + r15) * 256 + (((ks * 4 + gq) ^ rx) * 16);
        frag_u s, a, e;
        s.v = *(const bf16x8*)(rb + aoff);
        e.v = *(const bf16x8*)(rb + 16384 + aoff);
        a.u[0] = s.u[0] & 0x7FFF7FFFu;
        a.u[1] = s.u[1] & 0x7FFF7FFFu;
        a.u[2] = s.u[2] & 0x7FFF7FFFu;
        a.u[3] = s.u[3] & 0x7FFF7FFFu;
        accn[mf] = MFMA(s.v, bm, accn[mf], 0, 0, 0);
        accn[mf] = MFMA(a.v, bp, accn[mf], 0, 0, 0);
        acce[mf] = MFMA(e.v, be, acce[mf], 0, 0, 0);
      }
    }
    // ---- pack(i+1) into buf[(i+1)&1]; then issue adj(i+2) ----
    if (i < 11) {
      char* wbuf = smem + ((i + 1) & 1) * 32768;
#pragma unroll
      for (int j = 0; j < 4; ++j) {
        const float4 u = rr[2 * j], v = rr[2 * j + 1];
        uint4 P;
        if (isNode) {
          P.x = pk_sgn(u.x, u.y); P.y = pk_sgn(u.z, u.w);
          P.z = pk_sgn(v.x, v.y); P.w = pk_sgn(v.z, v.w);
        } else {
          P.x = pk_bf(u.x, u.y);  P.y = pk_bf(u.z, u.w);
          P.z = pk_bf(v.x, v.y);  P.w = pk_bf(v.z, v.w);
        }
        *(uint4*)(wbuf + wOffs[j]) = P;
      }
      if (i < 10) {
        const float* s2 = src + (i + 2) * 128;
#pragma unroll
        for (int m = 0; m < 8; ++m) rr[m] = *(const float4*)(s2 + m * 4);
      }
    }
    asm volatile("s_waitcnt lgkmcnt(0)" ::: "memory");
    __builtin_amdgcn_sched_barrier(0);
    __builtin_amdgcn_s_barrier();
  }

  // ---- accumulate partials: C/D frag row=(lane>>4)*4+q, col=lane&15 ----
  const int col = w * 16 + r15;
#pragma unroll
  for (int mf = 0; mf < 4; ++mf) {
    const f32x4 nv = accn[mf];
    const f32x4 ev = acce[mf];
#pragma unroll
    for (int q = 0; q < 4; ++q) {
      const size_t idx = (size_t)(row0 + mf * 16 + gq * 4 + q) * 128 + col;
      unsafeAtomicAdd(&node_part[idx], nv[q]);
      unsafeAtomicAdd(&edge_part[idx], ev[q]);
    }
  }
}

// ---------------------------------------------------------------------------
// Kernel 3: out = relu(node_part + node_bias) + edge_part + edge_bias
// ---------------------------------------------------------------------------
__global__ __launch_bounds__(256) void fgc_final(
    const float* __restrict__ node_part, const float* __restrict__ edge_part,
    const float* __restrict__ node_bias, const float* __restrict__ edge_bias,
    float* __restrict__ out) {
  const int idx = blockIdx.x * 256 + threadIdx.x;  // one float4 each
  const int col = (idx * 4) & 127;
  const float4 n = ((const float4*)node_part)[idx];
  const float4 e = ((const float4*)edge_part)[idx];
  const float4 nb = *(const float4*)(node_bias + col);
  const float4 eb = *(const float4*)(edge_bias + col);
  float4 o;
  o.x = fmaxf(n.x + nb.x, 0.f) + e.x + eb.x;
  o.y = fmaxf(n.y + nb.y, 0.f) + e.y + eb.y;
  o.z = fmaxf(n.z + nb.z, 0.f) + e.z + eb.z;
  o.w = fmaxf(n.w + nb.w, 0.f) + e.w + eb.w;
  ((float4*)out)[idx] = o;
}

extern "C" void kernel_launch(void* const* d_in, const int* in_sizes, int n_in,
                              void* d_out, int out_size, void* d_ws, size_t ws_size,
                              hipStream_t stream) {
  const float* feats = (const float*)d_in[0];
  const float* node_adj = (const float*)d_in[1];
  const float* edge_adj = (const float*)d_in[2];
  const float* node_w = (const float*)d_in[3];
  const float* node_b = (const float*)d_in[4];
  const float* edge_w = (const float*)d_in[5];
  const float* edge_b = (const float*)d_in[6];
  uint16_t* gt = (uint16_t*)d_ws;                 // 9.44 MB
  float* node_part = (float*)d_ws + NPART_OFF;    // 6.29 MB
  float* edge_part = (float*)d_ws + EPART_OFF;    // 6.29 MB

  gw_kernel<<<768, 256, 0, stream>>>(feats, node_w, edge_w, gt);
  hipMemsetAsync((char*)d_ws + 9437184, 0, 2 * 6291456, stream);
  fgc_main<<<1536, 512, 0, stream>>>(node_adj, edge_adj, gt,
                                     node_part, edge_part);
  fgc_final<<<1536, 256, 0, stream>>>(node_part, edge_part, node_b, edge_b,
                                      (float*)d_out);
}